// Round 9
// baseline (591.617 us; speedup 1.0000x reference)
//
#include <hip/hip_runtime.h>

constexpr int N_NODES = 50000;
constexpr int N_EDGES = 1600000;
constexpr int NREL    = 12;
constexpr int F_INPUT = 64;
constexpr int HID     = 128;
constexpr int NCLS    = 10;
constexpr int NGRAPH  = 256;
constexpr int NSEG    = N_NODES * NREL;       // 600000
constexpr float BN_EPS = 1e-5f;

// relation grouping for LLC-blocked Z (chunk stays cache-resident)
constexpr int NRELA = 6;                      // group A: rels 0..5
constexpr int NRELB = 7;                      // group B: rels 6..11 + root(idx 6)

// counting-sort CSR parameters
constexpr int NB    = 391;                    // buckets of 128 nodes (dst >> 7)
constexpr int SEGB  = 128 * NREL;             // 1536 segments per bucket
constexpr int NBLK  = 392;                    // partition blocks
constexpr int PTPB  = 1024;
constexpr int EPB   = 4096;                   // edges per partition block (4/thread)

typedef float v4f __attribute__((ext_vector_type(4)));
typedef short s8b __attribute__((ext_vector_type(8)));

__device__ __forceinline__ unsigned f2bf(float f) {
    unsigned u = __float_as_uint(f);
    return (u + 0x7FFFu + ((u >> 16) & 1u)) >> 16;   // RNE fp32->bf16
}
__device__ __forceinline__ unsigned pack2(float a, float b) {
    return f2bf(a) | (f2bf(b) << 16);
}

// ---------------- fused prep: zero scratch + pack weights + cast x + pcnt ----------------
constexpr int PQ0 = 64;                        // bn1: 256 floats (uint4)
constexpr int PQ1 = PQ0 + 64;                  // bn2
constexpr int PQ2 = PQ1 + 8192;                // psum: 32768 floats
constexpr int PQ3 = PQ2 + 13 * F_INPUT * HID;  // pack_w1
constexpr int PQ4 = PQ3 + 13 * HID * HID;      // pack_w2
constexpr int PQ5 = PQ4 + N_NODES * F_INPUT / 4; // cast x (float4)
constexpr int PQ6 = PQ5 + NGRAPH;              // pcnt binary search
constexpr int PREP_BLOCKS = (PQ6 + 255) / 256;

__global__ void prep(const float* __restrict__ Wrel1, const float* __restrict__ root1,
                     const float* __restrict__ Wrel2, const float* __restrict__ root2,
                     const float* __restrict__ x, const int* __restrict__ batch,
                     ushort* __restrict__ Wp1, ushort* __restrict__ Wp2,
                     ushort* __restrict__ xb,
                     float* __restrict__ bn1, float* __restrict__ bn2,
                     float* __restrict__ psum, float* __restrict__ pcnt) {
    int tid = blockIdx.x * 256 + threadIdx.x;
    const uint4 z = make_uint4(0, 0, 0, 0);
    if (tid < PQ0) { reinterpret_cast<uint4*>(bn1)[tid] = z; return; }
    if (tid < PQ1) { reinterpret_cast<uint4*>(bn2)[tid - PQ0] = z; return; }
    if (tid < PQ2) { reinterpret_cast<uint4*>(psum)[tid - PQ1] = z; return; }
    if (tid < PQ3) {
        int idx = tid - PQ2;                       // 13 * 8192
        int r = idx >> 13, rem = idx & 8191;
        int k = rem >> 7, n = rem & 127;
        const float* W = (r < NREL) ? (Wrel1 + (size_t)r * 8192) : root1;
        float v = W[k * HID + n];
        int b = k >> 5, kk = k & 31;
        int j = (n & 7) * 16 + (n >> 3);           // col-permuted fragment row
        Wp1[(((size_t)(r * 2 + b)) * HID + j) * 32 + kk] = (ushort)f2bf(v);
        return;
    }
    if (tid < PQ4) {
        int idx = tid - PQ3;                       // 13 * 16384
        int r = idx >> 14, rem = idx & 16383;
        int k = rem >> 7, n = rem & 127;
        const float* W = (r < NREL) ? (Wrel2 + (size_t)r * 16384) : root2;
        float v = W[k * HID + n];
        int b = k >> 5, kk = k & 31;
        int j = (n & 7) * 16 + (n >> 3);
        Wp2[(((size_t)(r * 4 + b)) * HID + j) * 32 + kk] = (ushort)f2bf(v);
        return;
    }
    if (tid < PQ5) {
        int i = tid - PQ4;
        float4 v = reinterpret_cast<const float4*>(x)[i];
        uint2 o;
        o.x = pack2(v.x, v.y);
        o.y = pack2(v.z, v.w);
        reinterpret_cast<uint2*>(xb)[i] = o;
        return;
    }
    if (tid < PQ6) {
        int g = tid - PQ5;
        int lo0 = 0, hi0 = N_NODES;
        while (lo0 < hi0) { int m = (lo0 + hi0) >> 1; if (batch[m] < g) lo0 = m + 1; else hi0 = m; }
        int lo1 = lo0, hi1 = N_NODES;
        while (lo1 < hi1) { int m = (lo1 + hi1) >> 1; if (batch[m] < g + 1) lo1 = m + 1; else hi1 = m; }
        pcnt[g] = (float)(lo1 - lo0);
    }
}

// ---------------- counting-sort CSR build (no far atomics) ----------------

__global__ __launch_bounds__(PTPB)
void part_hist(const int* __restrict__ dst, int* __restrict__ histG) {
    __shared__ int h[NB];
    int t = threadIdx.x, blk = blockIdx.x;
    if (t < NB) h[t] = 0;
    __syncthreads();
    int base = blk * EPB;
#pragma unroll
    for (int it = 0; it < EPB / PTPB; ++it) {
        int e = base + it * PTPB + t;
        if (e < N_EDGES) atomicAdd(&h[dst[e] >> 7], 1);
    }
    __syncthreads();
    if (t < NB) histG[blk * NB + t] = h[t];
}

__global__ __launch_bounds__(512)
void part_scanA(const int* __restrict__ histG, int* __restrict__ cursorG,
                int* __restrict__ bucketTot) {
    __shared__ int s[512];
    int t = threadIdx.x, b = blockIdx.x;
    int v = (t < NBLK) ? histG[t * NB + b] : 0;
    s[t] = v;
    __syncthreads();
    for (int d = 1; d < 512; d <<= 1) {
        int x = (t >= d) ? s[t - d] : 0;
        __syncthreads();
        s[t] += x;
        __syncthreads();
    }
    if (t < NBLK) cursorG[t * NB + b] = s[t] - v;   // exclusive prefix
    if (t == NBLK - 1) bucketTot[b] = s[t];
}

__global__ __launch_bounds__(512)
void part_scanB(const int* __restrict__ bucketTot, int* __restrict__ bucketBase) {
    __shared__ int s[512];
    int t = threadIdx.x;
    int v = (t < NB) ? bucketTot[t] : 0;
    s[t] = v;
    __syncthreads();
    for (int d = 1; d < 512; d <<= 1) {
        int x = (t >= d) ? s[t - d] : 0;
        __syncthreads();
        s[t] += x;
        __syncthreads();
    }
    if (t <= NB) bucketBase[t] = (t == 0) ? 0 : s[t - 1];
}

__global__ __launch_bounds__(PTPB)
void part_scatter(const int* __restrict__ src, const int* __restrict__ dst,
                  const int* __restrict__ et, const int* __restrict__ cursorG,
                  const int* __restrict__ bucketBase, uint* __restrict__ ebuck) {
    __shared__ int cur[NB];
    int t = threadIdx.x, blk = blockIdx.x;
    if (t < NB) cur[t] = cursorG[blk * NB + t] + bucketBase[t];
    __syncthreads();
    int base = blk * EPB;
#pragma unroll
    for (int it = 0; it < EPB / PTPB; ++it) {
        int e = base + it * PTPB + t;
        if (e < N_EDGES) {
            int d = dst[e];
            int b = d >> 7;
            int pos = atomicAdd(&cur[b], 1);
            ebuck[pos] = (uint)src[e] | ((uint)(d & 127) << 16) | ((uint)et[e] << 23);
        }
    }
}

// P4: per-bucket finalize. zrow is CHUNK-RELATIVE: rel<6 -> rel, else rel-6.
__global__ __launch_bounds__(256)
void csr_finalize(const uint* __restrict__ ebuck, const int* __restrict__ bucketBase,
                  int* __restrict__ off, int* __restrict__ zrow, float* __restrict__ wgt) {
    __shared__ int cnt[SEGB];
    __shared__ int cur[SEGB];
    __shared__ float winv[SEGB];
    __shared__ int partial[256];
    int t = threadIdx.x, b = blockIdx.x;
    int eb0 = bucketBase[b], eb1 = bucketBase[b + 1];
#pragma unroll
    for (int i = 0; i < 6; ++i) cnt[t * 6 + i] = 0;
    __syncthreads();
    for (int e = eb0 + t; e < eb1; e += 256) {
        uint u = ebuck[e];
        int key = (int)((u >> 16) & 127) * NREL + (int)(u >> 23);
        atomicAdd(&cnt[key], 1);
    }
    __syncthreads();
    int loc[6];
    int sum = 0;
#pragma unroll
    for (int i = 0; i < 6; ++i) { loc[i] = sum; sum += cnt[t * 6 + i]; }
    partial[t] = sum;
    __syncthreads();
    for (int d = 1; d < 256; d <<= 1) {
        int v = (t >= d) ? partial[t - d] : 0;
        __syncthreads();
        partial[t] += v;
        __syncthreads();
    }
    int tbase = (t == 0) ? 0 : partial[t - 1];
    int nodeb = b * 128;
#pragma unroll
    for (int i = 0; i < 6; ++i) {
        int s = t * 6 + i;
        int gpos = eb0 + tbase + loc[i];
        cur[s] = gpos;
        int c = cnt[s];
        winv[s] = (c > 0) ? 1.0f / (float)c : 0.f;
        int node = nodeb + s / NREL;
        if (node < N_NODES) off[node * NREL + (s % NREL)] = gpos;
    }
    __syncthreads();
    for (int e = eb0 + t; e < eb1; e += 256) {
        uint u = ebuck[e];
        int rel = (int)(u >> 23);
        int key = (int)((u >> 16) & 127) * NREL + rel;
        int pos = atomicAdd(&cur[key], 1);
        int relc = (rel < NRELA) ? rel : rel - NRELA;
        zrow[pos] = relc * N_NODES + (int)(u & 0xFFFFu);
        wgt[pos] = winv[key];
    }
    if (b == 0 && t == 0) off[NSEG] = N_EDGES;
}

// ---------------- dense per-relation-group transform: Z[r] = X @ W_r ----------------
// NR matrices starting at Wp (already offset). Z chunk reused across passes (LLC-hot).

template <int F, int NR>
__launch_bounds__(256)
__global__ void gemm_rel(const ushort* __restrict__ xin, const ushort* __restrict__ Wp,
                         ushort* __restrict__ Z) {
    constexpr int FP2 = F + 8;
    constexpr int KB  = F / 32;
    constexpr int CHW = F / 4;            // bf16 elems per staging thread
    constexpr int NLD = CHW / 8;          // uint4 loads (2 or 4)
    __shared__ __align__(16) ushort A[64 * FP2];
    const int t = threadIdx.x;
    const int n0 = blockIdx.x * 64;
    const int nl = t >> 2, tid4 = t & 3;
    const int lane = t & 63, wave = t >> 6, q = lane >> 4, l16 = lane & 15;

    {
        int n = n0 + nl;
        uint4* dst = reinterpret_cast<uint4*>(A + nl * FP2 + tid4 * CHW);
        if (n < N_NODES) {
            const uint4* srcp =
                reinterpret_cast<const uint4*>(xin + (size_t)n * F + tid4 * CHW);
#pragma unroll
            for (int c = 0; c < NLD; ++c) dst[c] = srcp[c];
        } else {
            uint4 z = make_uint4(0, 0, 0, 0);
#pragma unroll
            for (int c = 0; c < NLD; ++c) dst[c] = z;
        }
    }
    __syncthreads();

    s8b afr[KB];
    const ushort* Arow = A + (wave * 16 + l16) * FP2 + q * 8;
#pragma unroll
    for (int b = 0; b < KB; ++b)
        afr[b] = *reinterpret_cast<const s8b*>(Arow + b * 32);

    const int rowb = n0 + wave * 16 + q * 4;
    for (int rel = 0; rel < NR; ++rel) {
        v4f acc[8];
#pragma unroll
        for (int nt = 0; nt < 8; ++nt) acc[nt] = (v4f){0.f, 0.f, 0.f, 0.f};
#pragma unroll
        for (int b = 0; b < KB; ++b) {
            const ushort* wb = Wp + ((size_t)(rel * KB + b) * HID + l16) * 32 + q * 8;
#pragma unroll
            for (int nt = 0; nt < 8; ++nt) {
                s8b bfb = *reinterpret_cast<const s8b*>(wb + (size_t)nt * 16 * 32);
                acc[nt] = __builtin_amdgcn_mfma_f32_16x16x32_bf16(afr[b], bfb, acc[nt], 0, 0, 0);
            }
        }
        ushort* zr = Z + (size_t)rel * ((size_t)N_NODES * HID);
#pragma unroll
        for (int rr = 0; rr < 4; ++rr) {
            int n = rowb + rr;
            if (n < N_NODES) {
                uint4 o;
                o.x = pack2(acc[0][rr], acc[1][rr]);
                o.y = pack2(acc[2][rr], acc[3][rr]);
                o.z = pack2(acc[4][rr], acc[5][rr]);
                o.w = pack2(acc[6][rr], acc[7][rr]);
                *reinterpret_cast<uint4*>(zr + (size_t)n * HID + l16 * 8) = o;
            }
        }
    }
}

// ---------------- aggregation over one relation group ----------------
// FIRST pass (rels 0..5): H = sum.  Second pass (rels 6..11 + root): H += prior,
// add root row (chunk idx 6) + bias, emit BN partials.

template <bool FIRST>
__launch_bounds__(256)
__global__ void agg_bn(const ushort* __restrict__ Z, const int* __restrict__ off,
                       const int* __restrict__ zrow, const float* __restrict__ wgt,
                       const float* __restrict__ bias,
                       float* __restrict__ H, float* __restrict__ bn_sum,
                       float* __restrict__ bn_sq) {
    __shared__ float RED[2][4][HID];
    const int t = threadIdx.x;
    const int lane = t & 63, wave = t >> 6;
    const int n0 = blockIdx.x * 32 + wave * 8;
    const float2 bv = FIRST ? make_float2(0.f, 0.f)
                            : *reinterpret_cast<const float2*>(bias + lane * 2);
    float ps0 = 0.f, ps1 = 0.f, pq0 = 0.f, pq1 = 0.f;

    for (int i = 0; i < 8; ++i) {
        int n = n0 + i;
        if (n >= N_NODES) break;
        int e0, ee;
        float a0, a1;
        if (FIRST) {
            e0 = off[n * NREL];
            ee = off[n * NREL + NRELA];
            a0 = 0.f; a1 = 0.f;
        } else {
            e0 = off[n * NREL + NRELA];
            ee = off[n * NREL + NREL];
            // prior partial + root (chunk row 6) + bias
            float2 hp = *reinterpret_cast<const float2*>(H + (size_t)n * HID + lane * 2);
            uint ur = *reinterpret_cast<const uint*>(
                Z + ((size_t)6 * N_NODES + n) * HID + lane * 2);
            a0 = hp.x + __uint_as_float(ur << 16) + bv.x;
            a1 = hp.y + __uint_as_float(ur & 0xFFFF0000u) + bv.y;
        }
        if (e0 < ee) {
            int elast = ee - 1;
            for (int e = e0; e < ee; e += 8) {
                int zr_[8];
                float w_[8];
#pragma unroll
                for (int j = 0; j < 8; ++j) {
                    int ec = min(e + j, elast);
                    zr_[j] = zrow[ec];
                    w_[j] = (e + j < ee) ? wgt[ec] : 0.f;
                }
                uint u_[8];
#pragma unroll
                for (int j = 0; j < 8; ++j)
                    u_[j] = *reinterpret_cast<const uint*>(
                        Z + (size_t)zr_[j] * HID + lane * 2);
#pragma unroll
                for (int j = 0; j < 8; ++j) {
                    a0 += __uint_as_float(u_[j] << 16) * w_[j];
                    a1 += __uint_as_float(u_[j] & 0xFFFF0000u) * w_[j];
                }
            }
        }
        *reinterpret_cast<float2*>(H + (size_t)n * HID + lane * 2) = make_float2(a0, a1);
        if (!FIRST) {
            ps0 += a0; ps1 += a1;
            pq0 += a0 * a0; pq1 += a1 * a1;
        }
    }
    if (!FIRST) {
        RED[0][wave][lane * 2] = ps0; RED[0][wave][lane * 2 + 1] = ps1;
        RED[1][wave][lane * 2] = pq0; RED[1][wave][lane * 2 + 1] = pq1;
        __syncthreads();
        int stat = t >> 7, col = t & 127;
        float v = RED[stat][0][col] + RED[stat][1][col] +
                  RED[stat][2][col] + RED[stat][3][col];
        if (stat == 0) atomicAdd(&bn_sum[col], v);
        else           atomicAdd(&bn_sq[col], v);
    }
}

// ---------------- BN(+finalize) + ReLU, emit bf16 ----------------

__global__ void bn_relu_bf16(const float* __restrict__ h, const float* __restrict__ bn_sum,
                             const float* __restrict__ bn_sq, const float* __restrict__ gamma,
                             const float* __restrict__ beta, ushort* __restrict__ outb) {
    __shared__ float CA[HID], CB[HID];
    int t = threadIdx.x;
    if (t < HID) {
        float mu = bn_sum[t] * (1.0f / N_NODES);
        float var = bn_sq[t] * (1.0f / N_NODES) - mu * mu;
        float a = gamma[t] / sqrtf(var + BN_EPS);
        CA[t] = a;
        CB[t] = beta[t] - a * mu;
    }
    __syncthreads();
    int i = blockIdx.x * 256 + t;  // float4 index
    constexpr int TOTAL = N_NODES * HID / 4;
    if (i < TOTAL) {
        int o4 = i & 31;
        float4 a = reinterpret_cast<const float4*>(CA)[o4];
        float4 b = reinterpret_cast<const float4*>(CB)[o4];
        float4 v = reinterpret_cast<const float4*>(h)[i];
        v.x = fmaxf(a.x * v.x + b.x, 0.f);
        v.y = fmaxf(a.y * v.y + b.y, 0.f);
        v.z = fmaxf(a.z * v.z + b.z, 0.f);
        v.w = fmaxf(a.w * v.w + b.w, 0.f);
        uint2 o;
        o.x = pack2(v.x, v.y);
        o.y = pack2(v.z, v.w);
        reinterpret_cast<uint2*>(outb)[i] = o;
    }
}

// ---------------- pooling (BN finalize + ReLU fused; batch sorted -> run-length) ----------------

__global__ void pool_bnrelu(const float* __restrict__ h, const float* __restrict__ bn_sum,
                            const float* __restrict__ bn_sq, const float* __restrict__ gamma,
                            const float* __restrict__ beta, const int* __restrict__ batch,
                            float* __restrict__ psum) {
    __shared__ float CA[HID], CB[HID];
    int t = threadIdx.x;
    if (t < HID) {
        float mu = bn_sum[t] * (1.0f / N_NODES);
        float var = bn_sq[t] * (1.0f / N_NODES) - mu * mu;
        float a = gamma[t] / sqrtf(var + BN_EPS);
        CA[t] = a;
        CB[t] = beta[t] - a * mu;
    }
    __syncthreads();
    int col = t & 127;
    int nb = blockIdx.x * 16 + (t >> 7) * 8;  // 8 consecutive nodes per thread
    float a = CA[col], b = CB[col];
    float run = 0.f;
    int curg = -1;
    for (int i = 0; i < 8; ++i) {
        int n = nb + i;
        if (n < N_NODES) {
            int g = batch[n];
            float v = fmaxf(a * h[(size_t)n * HID + col] + b, 0.f);
            if (g != curg) {
                if (curg >= 0) atomicAdd(&psum[curg * HID + col], run);
                run = 0.f;
                curg = g;
            }
            run += v;
        }
    }
    if (curg >= 0) atomicAdd(&psum[curg * HID + col], run);
}

__global__ void final_kernel(const float* __restrict__ psum, const float* __restrict__ pcnt,
                             const float* __restrict__ Wf, const float* __restrict__ bf,
                             float* __restrict__ out) {
    __shared__ float p[HID];
    int g = blockIdx.x, t = threadIdx.x;  // 64 threads
    float inv = 1.0f / fmaxf(pcnt[g], 1.0f);
    p[t] = psum[g * HID + t] * inv;
    p[t + 64] = psum[g * HID + t + 64] * inv;
    __syncthreads();
    if (t < NCLS) {
        float s = bf[t];
#pragma unroll 16
        for (int k = 0; k < HID; ++k) s += p[k] * Wf[k * NCLS + t];
        out[g * NCLS + t] = s;
    }
}

// ---------------- launch ----------------

extern "C" void kernel_launch(void* const* d_in, const int* in_sizes, int n_in,
                              void* d_out, int out_size, void* d_ws, size_t ws_size,
                              hipStream_t stream) {
    const float* x      = (const float*)d_in[0];
    const float* Wrel1  = (const float*)d_in[1];
    const float* root1  = (const float*)d_in[2];
    const float* bias1  = (const float*)d_in[3];
    const float* gamma1 = (const float*)d_in[4];
    const float* beta1  = (const float*)d_in[5];
    const float* Wrel2  = (const float*)d_in[6];
    const float* root2  = (const float*)d_in[7];
    const float* bias2  = (const float*)d_in[8];
    const float* gamma2 = (const float*)d_in[9];
    const float* beta2  = (const float*)d_in[10];
    const float* Wf     = (const float*)d_in[11];
    const float* bf     = (const float*)d_in[12];
    const int* ei       = (const int*)d_in[13];
    const int* et       = (const int*)d_in[14];
    const int* batch    = (const int*)d_in[15];
    const int* srcv = ei;
    const int* dstv = ei + N_EDGES;

    char* w = (char*)d_ws;
    auto alloc = [&](size_t bytes) -> char* {
        char* p = w;
        w += (bytes + 255) / 256 * 256;
        return p;
    };
    int* off     = (int*)alloc((size_t)(NSEG + 1) * 4);
    int* zrow    = (int*)alloc((size_t)N_EDGES * 4);
    float* wgt   = (float*)alloc((size_t)N_EDGES * 4);
    ushort* xb   = (ushort*)alloc((size_t)N_NODES * F_INPUT * 2);
    ushort* H1b  = (ushort*)alloc((size_t)N_NODES * HID * 2);
    ushort* Wp1  = (ushort*)alloc((size_t)13 * F_INPUT * HID * 2);
    ushort* Wp2  = (ushort*)alloc((size_t)13 * HID * HID * 2);
    float* bn1   = (float*)alloc(2 * HID * 4);  // sum | sq
    float* bn2   = (float*)alloc(2 * HID * 4);
    float* psum  = (float*)alloc((size_t)NGRAPH * HID * 4);
    float* pcnt  = (float*)alloc((size_t)NGRAPH * 4);
    float* Hbuf  = (float*)alloc((size_t)N_NODES * HID * 4);   // H1, later H2
    // overlay: counting-sort scratch dies before Z is written
    char* ovl    = alloc((size_t)NRELB * N_NODES * HID * 2);   // Z chunk (89.6 MB)
    int* histG      = (int*)ovl;                               // 392*391
    int* cursorG    = (int*)(ovl + (size_t)NBLK * NB * 4);
    int* bucketTot  = (int*)(ovl + (size_t)2 * NBLK * NB * 4);
    int* bucketBase = (int*)(ovl + (size_t)2 * NBLK * NB * 4 + (NB + 1) * 4 + 252);
    uint* ebuck     = (uint*)(ovl + (size_t)2 * NBLK * NB * 4 + 4096);
    ushort* Zb      = (ushort*)ovl;

    prep<<<PREP_BLOCKS, 256, 0, stream>>>(Wrel1, root1, Wrel2, root2, x, batch,
                                          Wp1, Wp2, xb, bn1, bn2, psum, pcnt);

    part_hist<<<NBLK, PTPB, 0, stream>>>(dstv, histG);
    part_scanA<<<NB, 512, 0, stream>>>(histG, cursorG, bucketTot);
    part_scanB<<<1, 512, 0, stream>>>(bucketTot, bucketBase);
    part_scatter<<<NBLK, PTPB, 0, stream>>>(srcv, dstv, et, cursorG, bucketBase, ebuck);
    csr_finalize<<<NB, 256, 0, stream>>>(ebuck, bucketBase, off, zrow, wgt);

    int gblk = (N_NODES + 63) / 64;   // 782
    int ablk = (N_NODES + 31) / 32;   // 1563

    const size_t WOFF1 = (size_t)NRELA * (F_INPUT / 32) * HID * 32;  // group-B weights, layer 1
    const size_t WOFF2 = (size_t)NRELA * (HID / 32) * HID * 32;      // group-B weights, layer 2

    // ---- layer 1 (LLC-blocked by relation group) ----
    gemm_rel<F_INPUT, NRELA><<<gblk, 256, 0, stream>>>(xb, Wp1, Zb);
    agg_bn<true><<<ablk, 256, 0, stream>>>(Zb, off, zrow, wgt, bias1, Hbuf, bn1, bn1 + HID);
    gemm_rel<F_INPUT, NRELB><<<gblk, 256, 0, stream>>>(xb, Wp1 + WOFF1, Zb);
    agg_bn<false><<<ablk, 256, 0, stream>>>(Zb, off, zrow, wgt, bias1, Hbuf, bn1, bn1 + HID);
    bn_relu_bf16<<<(N_NODES * HID / 4 + 255) / 256, 256, 0, stream>>>(Hbuf, bn1, bn1 + HID,
                                                                      gamma1, beta1, H1b);

    // ---- layer 2 ----
    gemm_rel<HID, NRELA><<<gblk, 256, 0, stream>>>(H1b, Wp2, Zb);
    agg_bn<true><<<ablk, 256, 0, stream>>>(Zb, off, zrow, wgt, bias2, Hbuf, bn2, bn2 + HID);
    gemm_rel<HID, NRELB><<<gblk, 256, 0, stream>>>(H1b, Wp2 + WOFF2, Zb);
    agg_bn<false><<<ablk, 256, 0, stream>>>(Zb, off, zrow, wgt, bias2, Hbuf, bn2, bn2 + HID);

    pool_bnrelu<<<(N_NODES + 15) / 16, 256, 0, stream>>>(Hbuf, bn2, bn2 + HID, gamma2, beta2,
                                                         batch, psum);
    final_kernel<<<NGRAPH, 64, 0, stream>>>(psum, pcnt, Wf, bf, (float*)d_out);
}

// Round 10
// 485.945 us; speedup vs baseline: 1.2175x; 1.2175x over previous
//
#include <hip/hip_runtime.h>

constexpr int N_NODES = 50000;
constexpr int N_EDGES = 1600000;
constexpr int NREL    = 12;
constexpr int F_INPUT = 64;
constexpr int HID     = 128;
constexpr int NCLS    = 10;
constexpr int NGRAPH  = 256;
constexpr int NSEG    = N_NODES * NREL;       // 600000
constexpr float BN_EPS = 1e-5f;

// counting-sort CSR parameters
constexpr int NB    = 391;                    // buckets of 128 nodes (dst >> 7)
constexpr int SEGB  = 128 * NREL;             // 1536 segments per bucket
constexpr int NBLK  = 392;                    // partition blocks
constexpr int PTPB  = 1024;
constexpr int EPB   = 4096;                   // edges per partition block (4/thread)

typedef float v4f __attribute__((ext_vector_type(4)));
typedef short s8b __attribute__((ext_vector_type(8)));

__device__ __forceinline__ unsigned f2bf(float f) {
    unsigned u = __float_as_uint(f);
    return (u + 0x7FFFu + ((u >> 16) & 1u)) >> 16;   // RNE fp32->bf16
}
__device__ __forceinline__ unsigned pack2(float a, float b) {
    return f2bf(a) | (f2bf(b) << 16);
}

// ---------------- fused prep: zero scratch + pack weights + cast x + pcnt ----------------
constexpr int PQ0 = 64;                        // bn1: 256 floats (uint4)
constexpr int PQ1 = PQ0 + 64;                  // bn2
constexpr int PQ2 = PQ1 + 8192;                // psum: 32768 floats
constexpr int PQ3 = PQ2 + 13 * F_INPUT * HID;  // pack_w1
constexpr int PQ4 = PQ3 + 13 * HID * HID;      // pack_w2
constexpr int PQ5 = PQ4 + N_NODES * F_INPUT / 4; // cast x (float4)
constexpr int PQ6 = PQ5 + NGRAPH;              // pcnt binary search
constexpr int PREP_BLOCKS = (PQ6 + 255) / 256;

__global__ void prep(const float* __restrict__ Wrel1, const float* __restrict__ root1,
                     const float* __restrict__ Wrel2, const float* __restrict__ root2,
                     const float* __restrict__ x, const int* __restrict__ batch,
                     ushort* __restrict__ Wp1, ushort* __restrict__ Wp2,
                     ushort* __restrict__ xb,
                     float* __restrict__ bn1, float* __restrict__ bn2,
                     float* __restrict__ psum, float* __restrict__ pcnt) {
    int tid = blockIdx.x * 256 + threadIdx.x;
    const uint4 z = make_uint4(0, 0, 0, 0);
    if (tid < PQ0) { reinterpret_cast<uint4*>(bn1)[tid] = z; return; }
    if (tid < PQ1) { reinterpret_cast<uint4*>(bn2)[tid - PQ0] = z; return; }
    if (tid < PQ2) { reinterpret_cast<uint4*>(psum)[tid - PQ1] = z; return; }
    if (tid < PQ3) {
        int idx = tid - PQ2;                       // 13 * 8192
        int r = idx >> 13, rem = idx & 8191;
        int k = rem >> 7, n = rem & 127;
        const float* W = (r < NREL) ? (Wrel1 + (size_t)r * 8192) : root1;
        float v = W[k * HID + n];
        int b = k >> 5, kk = k & 31;
        int j = (n & 7) * 16 + (n >> 3);           // col-permuted fragment row
        Wp1[(((size_t)(r * 2 + b)) * HID + j) * 32 + kk] = (ushort)f2bf(v);
        return;
    }
    if (tid < PQ4) {
        int idx = tid - PQ3;                       // 13 * 16384
        int r = idx >> 14, rem = idx & 16383;
        int k = rem >> 7, n = rem & 127;
        const float* W = (r < NREL) ? (Wrel2 + (size_t)r * 16384) : root2;
        float v = W[k * HID + n];
        int b = k >> 5, kk = k & 31;
        int j = (n & 7) * 16 + (n >> 3);
        Wp2[(((size_t)(r * 4 + b)) * HID + j) * 32 + kk] = (ushort)f2bf(v);
        return;
    }
    if (tid < PQ5) {
        int i = tid - PQ4;
        float4 v = reinterpret_cast<const float4*>(x)[i];
        uint2 o;
        o.x = pack2(v.x, v.y);
        o.y = pack2(v.z, v.w);
        reinterpret_cast<uint2*>(xb)[i] = o;
        return;
    }
    if (tid < PQ6) {
        int g = tid - PQ5;
        int lo0 = 0, hi0 = N_NODES;
        while (lo0 < hi0) { int m = (lo0 + hi0) >> 1; if (batch[m] < g) lo0 = m + 1; else hi0 = m; }
        int lo1 = lo0, hi1 = N_NODES;
        while (lo1 < hi1) { int m = (lo1 + hi1) >> 1; if (batch[m] < g + 1) lo1 = m + 1; else hi1 = m; }
        pcnt[g] = (float)(lo1 - lo0);
    }
}

// ---------------- counting-sort CSR build (no far atomics) ----------------

__global__ __launch_bounds__(PTPB)
void part_hist(const int* __restrict__ dst, int* __restrict__ histG) {
    __shared__ int h[NB];
    int t = threadIdx.x, blk = blockIdx.x;
    if (t < NB) h[t] = 0;
    __syncthreads();
    int base = blk * EPB;
#pragma unroll
    for (int it = 0; it < EPB / PTPB; ++it) {
        int e = base + it * PTPB + t;
        if (e < N_EDGES) atomicAdd(&h[dst[e] >> 7], 1);
    }
    __syncthreads();
    if (t < NB) histG[blk * NB + t] = h[t];
}

__global__ __launch_bounds__(512)
void part_scanA(const int* __restrict__ histG, int* __restrict__ cursorG,
                int* __restrict__ bucketTot) {
    __shared__ int s[512];
    int t = threadIdx.x, b = blockIdx.x;
    int v = (t < NBLK) ? histG[t * NB + b] : 0;
    s[t] = v;
    __syncthreads();
    for (int d = 1; d < 512; d <<= 1) {
        int x = (t >= d) ? s[t - d] : 0;
        __syncthreads();
        s[t] += x;
        __syncthreads();
    }
    if (t < NBLK) cursorG[t * NB + b] = s[t] - v;   // exclusive prefix
    if (t == NBLK - 1) bucketTot[b] = s[t];
}

__global__ __launch_bounds__(512)
void part_scanB(const int* __restrict__ bucketTot, int* __restrict__ bucketBase) {
    __shared__ int s[512];
    int t = threadIdx.x;
    int v = (t < NB) ? bucketTot[t] : 0;
    s[t] = v;
    __syncthreads();
    for (int d = 1; d < 512; d <<= 1) {
        int x = (t >= d) ? s[t - d] : 0;
        __syncthreads();
        s[t] += x;
        __syncthreads();
    }
    if (t <= NB) bucketBase[t] = (t == 0) ? 0 : s[t - 1];
}

__global__ __launch_bounds__(PTPB)
void part_scatter(const int* __restrict__ src, const int* __restrict__ dst,
                  const int* __restrict__ et, const int* __restrict__ cursorG,
                  const int* __restrict__ bucketBase, uint* __restrict__ ebuck) {
    __shared__ int cur[NB];
    int t = threadIdx.x, blk = blockIdx.x;
    if (t < NB) cur[t] = cursorG[blk * NB + t] + bucketBase[t];
    __syncthreads();
    int base = blk * EPB;
#pragma unroll
    for (int it = 0; it < EPB / PTPB; ++it) {
        int e = base + it * PTPB + t;
        if (e < N_EDGES) {
            int d = dst[e];
            int b = d >> 7;
            int pos = atomicAdd(&cur[b], 1);
            ebuck[pos] = (uint)src[e] | ((uint)(d & 127) << 16) | ((uint)et[e] << 23);
        }
    }
}

// P4: per-bucket finalize: LDS count 1536 keys, block scan, emit off/zrow/wgt
__global__ __launch_bounds__(256)
void csr_finalize(const uint* __restrict__ ebuck, const int* __restrict__ bucketBase,
                  int* __restrict__ off, int* __restrict__ zrow, float* __restrict__ wgt) {
    __shared__ int cnt[SEGB];
    __shared__ int cur[SEGB];
    __shared__ float winv[SEGB];
    __shared__ int partial[256];
    int t = threadIdx.x, b = blockIdx.x;
    int eb0 = bucketBase[b], eb1 = bucketBase[b + 1];
#pragma unroll
    for (int i = 0; i < 6; ++i) cnt[t * 6 + i] = 0;
    __syncthreads();
    for (int e = eb0 + t; e < eb1; e += 256) {
        uint u = ebuck[e];
        int key = (int)((u >> 16) & 127) * NREL + (int)(u >> 23);
        atomicAdd(&cnt[key], 1);
    }
    __syncthreads();
    int loc[6];
    int sum = 0;
#pragma unroll
    for (int i = 0; i < 6; ++i) { loc[i] = sum; sum += cnt[t * 6 + i]; }
    partial[t] = sum;
    __syncthreads();
    for (int d = 1; d < 256; d <<= 1) {
        int v = (t >= d) ? partial[t - d] : 0;
        __syncthreads();
        partial[t] += v;
        __syncthreads();
    }
    int tbase = (t == 0) ? 0 : partial[t - 1];
    int nodeb = b * 128;
#pragma unroll
    for (int i = 0; i < 6; ++i) {
        int s = t * 6 + i;
        int gpos = eb0 + tbase + loc[i];
        cur[s] = gpos;
        int c = cnt[s];
        winv[s] = (c > 0) ? 1.0f / (float)c : 0.f;
        int node = nodeb + s / NREL;
        if (node < N_NODES) off[node * NREL + (s % NREL)] = gpos;
    }
    __syncthreads();
    for (int e = eb0 + t; e < eb1; e += 256) {
        uint u = ebuck[e];
        int rel = (int)(u >> 23);
        int key = (int)((u >> 16) & 127) * NREL + rel;
        int pos = atomicAdd(&cur[key], 1);
        zrow[pos] = rel * N_NODES + (int)(u & 0xFFFFu);
        wgt[pos] = winv[key];
    }
    if (b == 0 && t == 0) off[NSEG] = N_EDGES;
}

// ---------------- dense per-relation transform: Z[r] = X @ W_r (13 rels, r=12 root) ----------------
// 128-node tile, wave owns 32 rows (2 subtiles). B fragments held in registers and
// reused across both subtiles -> halves weight reload traffic vs 64-node tiles.

template <int F>
__launch_bounds__(256)
__global__ void gemm_rel(const ushort* __restrict__ xin, const ushort* __restrict__ Wp,
                         ushort* __restrict__ Z) {
    constexpr int TN  = 128;
    constexpr int FP2 = F + 8;
    constexpr int KB  = F / 32;
    constexpr int CHW = F / 4;            // bf16 elems per staging thread-chunk
    constexpr int NLD = CHW / 8;          // uint4 loads per chunk
    __shared__ __align__(16) ushort A[TN * FP2];
    const int t = threadIdx.x;
    const int n0 = blockIdx.x * TN;
    const int lane = t & 63, wave = t >> 6, q = lane >> 4, l16 = lane & 15;

    // stage 128 rows (two 64-row groups; 4 threads/row, coalesced)
    {
        const int nl = t >> 2, tid4 = t & 3;
#pragma unroll
        for (int g = 0; g < 2; ++g) {
            int row = g * 64 + nl;
            int n = n0 + row;
            uint4* dstp = reinterpret_cast<uint4*>(A + row * FP2 + tid4 * CHW);
            if (n < N_NODES) {
                const uint4* srcp =
                    reinterpret_cast<const uint4*>(xin + (size_t)n * F + tid4 * CHW);
#pragma unroll
                for (int c = 0; c < NLD; ++c) dstp[c] = srcp[c];
            } else {
                uint4 zz = make_uint4(0, 0, 0, 0);
#pragma unroll
                for (int c = 0; c < NLD; ++c) dstp[c] = zz;
            }
        }
    }
    __syncthreads();

    const int rowbase = wave * 32;   // wave owns rows [rowbase, rowbase+32)
    for (int rel = 0; rel < 13; ++rel) {
        v4f acc[2][8];
#pragma unroll
        for (int st = 0; st < 2; ++st)
#pragma unroll
            for (int nt = 0; nt < 8; ++nt) acc[st][nt] = (v4f){0.f, 0.f, 0.f, 0.f};
#pragma unroll
        for (int b = 0; b < KB; ++b) {
            s8b bfr[8];
            const ushort* wb = Wp + ((size_t)(rel * KB + b) * HID + l16) * 32 + q * 8;
#pragma unroll
            for (int nt = 0; nt < 8; ++nt)
                bfr[nt] = *reinterpret_cast<const s8b*>(wb + (size_t)nt * 16 * 32);
#pragma unroll
            for (int st = 0; st < 2; ++st) {
                s8b af = *reinterpret_cast<const s8b*>(
                    A + (rowbase + st * 16 + l16) * FP2 + b * 32 + q * 8);
#pragma unroll
                for (int nt = 0; nt < 8; ++nt)
                    acc[st][nt] =
                        __builtin_amdgcn_mfma_f32_16x16x32_bf16(af, bfr[nt], acc[st][nt], 0, 0, 0);
            }
        }
        // lane l16 owns logical cols l16*8..l16*8+7 (Wp is col-permuted)
        ushort* zr = Z + (size_t)rel * ((size_t)N_NODES * HID);
#pragma unroll
        for (int st = 0; st < 2; ++st) {
            int rowb = n0 + rowbase + st * 16 + q * 4;
#pragma unroll
            for (int rr = 0; rr < 4; ++rr) {
                int n = rowb + rr;
                if (n < N_NODES) {
                    uint4 o;
                    o.x = pack2(acc[st][0][rr], acc[st][1][rr]);
                    o.y = pack2(acc[st][2][rr], acc[st][3][rr]);
                    o.z = pack2(acc[st][4][rr], acc[st][5][rr]);
                    o.w = pack2(acc[st][6][rr], acc[st][7][rr]);
                    *reinterpret_cast<uint4*>(zr + (size_t)n * HID + l16 * 8) = o;
                }
            }
        }
    }
}

// ---------------- aggregation: H[n] = sum_e wgt[e]*Z[zrow[e]] + Z[12][n] + bias ----------------
// One wave per node, 8 nodes/wave, 8-wide clamped unroll = 8 independent
// 256B wave-loads in flight. BN partial stats fused.

__launch_bounds__(256)
__global__ void agg_bn(const ushort* __restrict__ Z, const int* __restrict__ off,
                       const int* __restrict__ zrow, const float* __restrict__ wgt,
                       const float* __restrict__ bias,
                       float* __restrict__ H, float* __restrict__ bn_sum,
                       float* __restrict__ bn_sq) {
    __shared__ float RED[2][4][HID];
    const int t = threadIdx.x;
    const int lane = t & 63, wave = t >> 6;
    const int n0 = blockIdx.x * 32 + wave * 8;
    const float2 bv = *reinterpret_cast<const float2*>(bias + lane * 2);
    float ps0 = 0.f, ps1 = 0.f, pq0 = 0.f, pq1 = 0.f;

    for (int i = 0; i < 8; ++i) {
        int n = n0 + i;
        if (n >= N_NODES) break;
        int e0 = off[n * NREL];
        int ee = off[n * NREL + NREL];
        uint ur = *reinterpret_cast<const uint*>(
            Z + ((size_t)12 * N_NODES + n) * HID + lane * 2);
        float a0 = __uint_as_float(ur << 16) + bv.x;
        float a1 = __uint_as_float(ur & 0xFFFF0000u) + bv.y;
        int elast = ee - 1;
        for (int e = e0; e < ee; e += 8) {
            int zr_[8];
            float w_[8];
#pragma unroll
            for (int j = 0; j < 8; ++j) {
                int ec = min(e + j, elast);
                zr_[j] = zrow[ec];
                w_[j] = (e + j < ee) ? wgt[ec] : 0.f;
            }
            uint u_[8];
#pragma unroll
            for (int j = 0; j < 8; ++j)
                u_[j] = *reinterpret_cast<const uint*>(
                    Z + (size_t)zr_[j] * HID + lane * 2);
#pragma unroll
            for (int j = 0; j < 8; ++j) {
                a0 += __uint_as_float(u_[j] << 16) * w_[j];
                a1 += __uint_as_float(u_[j] & 0xFFFF0000u) * w_[j];
            }
        }
        *reinterpret_cast<float2*>(H + (size_t)n * HID + lane * 2) = make_float2(a0, a1);
        ps0 += a0; ps1 += a1;
        pq0 += a0 * a0; pq1 += a1 * a1;
    }
    RED[0][wave][lane * 2] = ps0; RED[0][wave][lane * 2 + 1] = ps1;
    RED[1][wave][lane * 2] = pq0; RED[1][wave][lane * 2 + 1] = pq1;
    __syncthreads();
    {
        int stat = t >> 7, col = t & 127;
        float v = RED[stat][0][col] + RED[stat][1][col] +
                  RED[stat][2][col] + RED[stat][3][col];
        if (stat == 0) atomicAdd(&bn_sum[col], v);
        else           atomicAdd(&bn_sq[col], v);
    }
}

// ---------------- BN(+finalize) + ReLU, emit bf16 ----------------

__global__ void bn_relu_bf16(const float* __restrict__ h, const float* __restrict__ bn_sum,
                             const float* __restrict__ bn_sq, const float* __restrict__ gamma,
                             const float* __restrict__ beta, ushort* __restrict__ outb) {
    __shared__ float CA[HID], CB[HID];
    int t = threadIdx.x;
    if (t < HID) {
        float mu = bn_sum[t] * (1.0f / N_NODES);
        float var = bn_sq[t] * (1.0f / N_NODES) - mu * mu;
        float a = gamma[t] / sqrtf(var + BN_EPS);
        CA[t] = a;
        CB[t] = beta[t] - a * mu;
    }
    __syncthreads();
    int i = blockIdx.x * 256 + t;  // float4 index
    constexpr int TOTAL = N_NODES * HID / 4;
    if (i < TOTAL) {
        int o4 = i & 31;
        float4 a = reinterpret_cast<const float4*>(CA)[o4];
        float4 b = reinterpret_cast<const float4*>(CB)[o4];
        float4 v = reinterpret_cast<const float4*>(h)[i];
        v.x = fmaxf(a.x * v.x + b.x, 0.f);
        v.y = fmaxf(a.y * v.y + b.y, 0.f);
        v.z = fmaxf(a.z * v.z + b.z, 0.f);
        v.w = fmaxf(a.w * v.w + b.w, 0.f);
        uint2 o;
        o.x = pack2(v.x, v.y);
        o.y = pack2(v.z, v.w);
        reinterpret_cast<uint2*>(outb)[i] = o;
    }
}

// ---------------- pooling (BN finalize + ReLU fused; batch sorted -> run-length) ----------------

__global__ void pool_bnrelu(const float* __restrict__ h, const float* __restrict__ bn_sum,
                            const float* __restrict__ bn_sq, const float* __restrict__ gamma,
                            const float* __restrict__ beta, const int* __restrict__ batch,
                            float* __restrict__ psum) {
    __shared__ float CA[HID], CB[HID];
    int t = threadIdx.x;
    if (t < HID) {
        float mu = bn_sum[t] * (1.0f / N_NODES);
        float var = bn_sq[t] * (1.0f / N_NODES) - mu * mu;
        float a = gamma[t] / sqrtf(var + BN_EPS);
        CA[t] = a;
        CB[t] = beta[t] - a * mu;
    }
    __syncthreads();
    int col = t & 127;
    int nb = blockIdx.x * 16 + (t >> 7) * 8;  // 8 consecutive nodes per thread
    float a = CA[col], b = CB[col];
    float run = 0.f;
    int curg = -1;
    for (int i = 0; i < 8; ++i) {
        int n = nb + i;
        if (n < N_NODES) {
            int g = batch[n];
            float v = fmaxf(a * h[(size_t)n * HID + col] + b, 0.f);
            if (g != curg) {
                if (curg >= 0) atomicAdd(&psum[curg * HID + col], run);
                run = 0.f;
                curg = g;
            }
            run += v;
        }
    }
    if (curg >= 0) atomicAdd(&psum[curg * HID + col], run);
}

__global__ void final_kernel(const float* __restrict__ psum, const float* __restrict__ pcnt,
                             const float* __restrict__ Wf, const float* __restrict__ bf,
                             float* __restrict__ out) {
    __shared__ float p[HID];
    int g = blockIdx.x, t = threadIdx.x;  // 64 threads
    float inv = 1.0f / fmaxf(pcnt[g], 1.0f);
    p[t] = psum[g * HID + t] * inv;
    p[t + 64] = psum[g * HID + t + 64] * inv;
    __syncthreads();
    if (t < NCLS) {
        float s = bf[t];
#pragma unroll 16
        for (int k = 0; k < HID; ++k) s += p[k] * Wf[k * NCLS + t];
        out[g * NCLS + t] = s;
    }
}

// ---------------- launch ----------------

extern "C" void kernel_launch(void* const* d_in, const int* in_sizes, int n_in,
                              void* d_out, int out_size, void* d_ws, size_t ws_size,
                              hipStream_t stream) {
    const float* x      = (const float*)d_in[0];
    const float* Wrel1  = (const float*)d_in[1];
    const float* root1  = (const float*)d_in[2];
    const float* bias1  = (const float*)d_in[3];
    const float* gamma1 = (const float*)d_in[4];
    const float* beta1  = (const float*)d_in[5];
    const float* Wrel2  = (const float*)d_in[6];
    const float* root2  = (const float*)d_in[7];
    const float* bias2  = (const float*)d_in[8];
    const float* gamma2 = (const float*)d_in[9];
    const float* beta2  = (const float*)d_in[10];
    const float* Wf     = (const float*)d_in[11];
    const float* bf     = (const float*)d_in[12];
    const int* ei       = (const int*)d_in[13];
    const int* et       = (const int*)d_in[14];
    const int* batch    = (const int*)d_in[15];
    const int* srcv = ei;
    const int* dstv = ei + N_EDGES;

    char* w = (char*)d_ws;
    auto alloc = [&](size_t bytes) -> char* {
        char* p = w;
        w += (bytes + 255) / 256 * 256;
        return p;
    };
    int* off     = (int*)alloc((size_t)(NSEG + 1) * 4);
    int* zrow    = (int*)alloc((size_t)N_EDGES * 4);
    float* wgt   = (float*)alloc((size_t)N_EDGES * 4);
    ushort* xb   = (ushort*)alloc((size_t)N_NODES * F_INPUT * 2);
    ushort* H1b  = (ushort*)alloc((size_t)N_NODES * HID * 2);
    ushort* Wp1  = (ushort*)alloc((size_t)13 * F_INPUT * HID * 2);
    ushort* Wp2  = (ushort*)alloc((size_t)13 * HID * HID * 2);
    float* bn1   = (float*)alloc(2 * HID * 4);  // sum | sq
    float* bn2   = (float*)alloc(2 * HID * 4);
    float* psum  = (float*)alloc((size_t)NGRAPH * HID * 4);
    float* pcnt  = (float*)alloc((size_t)NGRAPH * 4);
    float* Hbuf  = (float*)alloc((size_t)N_NODES * HID * 4);   // H1, later H2
    // overlay: counting-sort scratch dies before Z is written
    char* ovl    = alloc((size_t)13 * N_NODES * HID * 2);      // Z (166.4 MB)
    int* histG      = (int*)ovl;                               // 392*391
    int* cursorG    = (int*)(ovl + (size_t)NBLK * NB * 4);
    int* bucketTot  = (int*)(ovl + (size_t)2 * NBLK * NB * 4);
    int* bucketBase = (int*)(ovl + (size_t)2 * NBLK * NB * 4 + (NB + 1) * 4 + 252);
    uint* ebuck     = (uint*)(ovl + (size_t)2 * NBLK * NB * 4 + 4096);
    ushort* Zb      = (ushort*)ovl;

    prep<<<PREP_BLOCKS, 256, 0, stream>>>(Wrel1, root1, Wrel2, root2, x, batch,
                                          Wp1, Wp2, xb, bn1, bn2, psum, pcnt);

    part_hist<<<NBLK, PTPB, 0, stream>>>(dstv, histG);
    part_scanA<<<NB, 512, 0, stream>>>(histG, cursorG, bucketTot);
    part_scanB<<<1, 512, 0, stream>>>(bucketTot, bucketBase);
    part_scatter<<<NBLK, PTPB, 0, stream>>>(srcv, dstv, et, cursorG, bucketBase, ebuck);
    csr_finalize<<<NB, 256, 0, stream>>>(ebuck, bucketBase, off, zrow, wgt);

    int gblk = (N_NODES + 127) / 128;  // 391
    int ablk = (N_NODES + 31) / 32;    // 1563

    // ---- layer 1 ----
    gemm_rel<F_INPUT><<<gblk, 256, 0, stream>>>(xb, Wp1, Zb);
    agg_bn<<<ablk, 256, 0, stream>>>(Zb, off, zrow, wgt, bias1, Hbuf, bn1, bn1 + HID);
    bn_relu_bf16<<<(N_NODES * HID / 4 + 255) / 256, 256, 0, stream>>>(Hbuf, bn1, bn1 + HID,
                                                                      gamma1, beta1, H1b);

    // ---- layer 2 ----
    gemm_rel<HID><<<gblk, 256, 0, stream>>>(H1b, Wp2, Zb);
    agg_bn<<<ablk, 256, 0, stream>>>(Zb, off, zrow, wgt, bias2, Hbuf, bn2, bn2 + HID);

    pool_bnrelu<<<(N_NODES + 15) / 16, 256, 0, stream>>>(Hbuf, bn2, bn2 + HID, gamma2, beta2,
                                                         batch, psum);
    final_kernel<<<NGRAPH, 64, 0, stream>>>(psum, pcnt, Wf, bf, (float*)d_out);
}